// Round 14
// baseline (205.791 us; speedup 1.0000x reference)
//
#include <hip/hip_runtime.h>
#include <math.h>

#define N_NODES 20000
#define N_EDGES 640000
#define DD 128
#define RR 32
#define HH 128
#define PI_F 3.14159265358979323846f

// prep_kernel block ranges
#define NPACK 416      // 106496 packed weights / 256
#define NLN   5000     // 20000 nodes / 4 rows per block
#define NHIST 2500     // 640000 edges / 256

typedef short bf16x8 __attribute__((ext_vector_type(8)));
typedef float f32x4 __attribute__((ext_vector_type(4)));
typedef __bf16 bf16x2_t __attribute__((ext_vector_type(2)));

__device__ __forceinline__ float silu_f(float x) {
    return x * __builtin_amdgcn_rcpf(1.0f + __expf(-x));
}
__device__ __forceinline__ float sigmoid_f(float x) {
    return __builtin_amdgcn_rcpf(1.0f + __expf(-x));
}
__device__ __forceinline__ unsigned short f2bf(float x) {
    __bf16 h = (__bf16)x;
    return __builtin_bit_cast(unsigned short, h);
}
__device__ __forceinline__ unsigned pk2(float lo, float hi) {
    bf16x2_t v;
    v[0] = (__bf16)lo; v[1] = (__bf16)hi;
    return __builtin_bit_cast(unsigned, v);
}
__device__ __forceinline__ bf16x8 frag8(float4 a, float4 b) {
    union { unsigned u[4]; bf16x8 v; } r;
    r.u[0] = pk2(a.x, a.y); r.u[1] = pk2(a.z, a.w);
    r.u[2] = pk2(b.x, b.y); r.u[3] = pk2(b.z, b.w);
    return r.v;
}

// pack W[K][F] fp32 -> bf16 MFMA-A-fragment order:
// packed[((s*NT + t)*64 + l)*8 + j] = W[s*32 + (l>>4)*8 + j][t*16 + (l&15)]
__device__ __forceinline__ unsigned short pack_one(const float* __restrict__ src,
                                                   int o, int F) {
    int NT = F >> 4;
    int j = o & 7;
    int l = (o >> 3) & 63;
    int rest = o >> 9;
    int t = rest % NT;
    int s = rest / NT;
    int k = s * 32 + ((l >> 4) << 3) + j;
    int f = t * 16 + (l & 15);
    return f2bf(src[(size_t)k * F + f]);
}

// ---------------- prep: weight packs + LayerNorm + histogram in one launch ---
__global__ __launch_bounds__(256) void prep_kernel(
    const float* __restrict__ eg_w1, const float* __restrict__ wm_w1,
    const float* __restrict__ wm_w2, const float* __restrict__ wm_w3,
    const float* __restrict__ mm_w1, const float* __restrict__ mm_w2,
    const float* __restrict__ sl_w,  const float* __restrict__ ul_w,
    unsigned short* __restrict__ wp,
    const float* __restrict__ x, const float* __restrict__ g,
    const float* __restrict__ b, float* __restrict__ xn,
    const int* __restrict__ edst, const float* __restrict__ elen,
    int* __restrict__ cnt)
{
    const int blk = blockIdx.x;
    if (blk < NPACK) {
        int o = blk * 256 + threadIdx.x;
        unsigned short v;
        if      (o < 4096)   v = pack_one(eg_w1, o,          HH);
        else if (o < 8192)   v = pack_one(wm_w1, o - 4096,   HH);
        else if (o < 24576)  v = pack_one(wm_w2, o - 8192,   HH);
        else if (o < 40960)  v = pack_one(wm_w3, o - 24576,  DD);
        else if (o < 57344)  v = pack_one(mm_w1, o - 40960,  HH);
        else if (o < 73728)  v = pack_one(mm_w2, o - 57344,  DD);
        else if (o < 90112)  v = pack_one(sl_w,  o - 73728,  DD);
        else                 v = pack_one(ul_w,  o - 90112,  DD);
        wp[o] = v;
    } else if (blk < NPACK + NLN) {
        int wid = ((blk - NPACK) * 256 + threadIdx.x) >> 6;
        int lane = threadIdx.x & 63;
        if (wid >= N_NODES) return;
        const float* row = x + (size_t)wid * DD;
        float v0 = row[lane], v1 = row[lane + 64];
        float s = v0 + v1, sq = v0 * v0 + v1 * v1;
        #pragma unroll
        for (int o = 32; o > 0; o >>= 1) { s += __shfl_xor(s, o); sq += __shfl_xor(sq, o); }
        float mu = s * (1.0f / 128.0f);
        float var = sq * (1.0f / 128.0f) - mu * mu;
        float inv = rsqrtf(var + 1e-5f);
        float* orow = xn + (size_t)wid * DD;
        orow[lane]      = (v0 - mu) * inv * g[lane]      + b[lane];
        orow[lane + 64] = (v1 - mu) * inv * g[lane + 64] + b[lane + 64];
    } else {
        int e = (blk - NPACK - NLN) * 256 + threadIdx.x;
        if (e < N_EDGES && elen[e] <= 5.0f) atomicAdd(&cnt[edst[e]], 1);
    }
}

// ---------------- parallel scan over node counts ----------------
__global__ __launch_bounds__(1024) void scan_kernel(const int* __restrict__ cnt,
                                                    int* __restrict__ offs,
                                                    int* __restrict__ cursor) {
    __shared__ int part[1024];
    const int t = threadIdx.x;
    const int per = 20;
    const int base = t * per;
    int s = 0;
    for (int i = 0; i < per; ++i) {
        int idx = base + i;
        if (idx < N_NODES) s += cnt[idx];
    }
    part[t] = s;
    __syncthreads();
    for (int off = 1; off < 1024; off <<= 1) {
        int v = (t >= off) ? part[t - off] : 0;
        __syncthreads();
        part[t] += v;
        __syncthreads();
    }
    int run = part[t] - s;
    for (int i = 0; i < per; ++i) {
        int idx = base + i;
        if (idx < N_NODES) {
            offs[idx] = run;
            cursor[idx] = run;
            run += cnt[idx];
        }
    }
    if (t == 1023) offs[N_NODES] = part[1023];
}

// ---------------- fill: coalesced reads -> 16B edge records at perm pos -----
__global__ __launch_bounds__(256) void fill_kernel(const int* __restrict__ esrc,
                                                   const int* __restrict__ edst,
                                                   const float* __restrict__ elen,
                                                   int* __restrict__ cursor,
                                                   int4* __restrict__ erec) {
    int e = blockIdx.x * 256 + threadIdx.x;
    if (e >= N_EDGES) return;
    float len = elen[e];
    if (len <= 5.0f) {
        int d = edst[e];
        int pos = atomicAdd(&cursor[d], 1);
        float cut = 0.5f * (__cosf(PI_F * len * 0.2f) + 1.0f);
        int4 rec;
        rec.x = e;
        rec.y = esrc[e];
        rec.z = d;
        rec.w = __float_as_int(cut);
        erec[pos] = rec;
    }
}

// ---------------- edge MLP + per-wave segmented scatter ----------------
// 4 waves x 32 dst-sorted edges. Distance-2 A-frag prefetch in L2/L3 and
// distance-1 xn-gather pipeline (uses the free VGPR headroom below the
// 128-reg / 4-waves-per-SIMD LDS-bound occupancy point). No barrier.
__global__ __launch_bounds__(256, 4) void edge_seg_kernel(
    const float* __restrict__ xn,
    const float* __restrict__ rbf,
    const int4* __restrict__ erec, const int* __restrict__ nlive_p,
    const unsigned short* __restrict__ wp_eg1, const unsigned short* __restrict__ wp_w1,
    const unsigned short* __restrict__ wp_w2,  const unsigned short* __restrict__ wp_w3,
    const float* __restrict__ eg_b1, const float* __restrict__ eg_w2,
    const float* __restrict__ eg_b2,
    const float* __restrict__ wm_b1, const float* __restrict__ wm_b2,
    const float* __restrict__ wm_b3,
    float* __restrict__ agg, float* __restrict__ nrm)
{
    __shared__ unsigned short act[4][32 * 136];
    __shared__ float ew_s[128];
    __shared__ int   dst_s[128];

    const int nlive = nlive_p[0];
    if (blockIdx.x * 128 >= nlive) return;

    const int tid  = threadIdx.x;
    const int w    = tid >> 6;
    const int lane = tid & 63;
    const int er   = lane & 15;
    const int kq   = lane >> 4;

    const int g0 = blockIdx.x * 128 + w * 32 + er;
    const int g1 = g0 + 16;
    const bool v0 = g0 < nlive, v1 = g1 < nlive;
    const int4 r0 = erec[v0 ? g0 : nlive - 1];
    const int4 r1 = erec[v1 ? g1 : nlive - 1];

    const int e0 = r0.x, src0 = r0.y, dst0 = r0.z;
    const int e1 = r1.x, src1 = r1.y, dst1 = r1.z;
    const float cut0 = v0 ? __int_as_float(r0.w) : 0.0f;
    const float cut1 = v1 ? __int_as_float(r1.w) : 0.0f;

    const float4* rp = (const float4*)(rbf + (size_t)e0 * RR + kq * 8);
    bf16x8 bfr0 = frag8(rp[0], rp[1]);
    const float4* rq = (const float4*)(rbf + (size_t)e1 * RR + kq * 8);
    bf16x8 bfr1 = frag8(rq[0], rq[1]);

    unsigned short* buf = &act[w][0];

    // ---- gate + L1 fused, distance-1 A-frag prefetch, bias in C-init ----
    float pd0 = 0.0f, pd1 = 0.0f;
    {
        bf16x8 agc = *(const bf16x8*)(wp_eg1 + (size_t)lane * 8);
        bf16x8 a1c = *(const bf16x8*)(wp_w1  + (size_t)lane * 8);
        #pragma unroll
        for (int t = 0; t < 8; ++t) {
            const int tn = (t + 1) & 7;
            bf16x8 agn = *(const bf16x8*)(wp_eg1 + ((size_t)tn * 64 + lane) * 8);
            bf16x8 a1n = *(const bf16x8*)(wp_w1  + ((size_t)tn * 64 + lane) * 8);
            float4 gb = *(const float4*)(eg_b1 + t * 16 + kq * 4);
            float4 b1 = *(const float4*)(wm_b1 + t * 16 + kq * 4);
            f32x4 cg0 = {gb.x, gb.y, gb.z, gb.w};
            f32x4 cg1 = cg0;
            f32x4 c10 = {b1.x, b1.y, b1.z, b1.w};
            f32x4 c11 = c10;
            cg0 = __builtin_amdgcn_mfma_f32_16x16x32_bf16(agc, bfr0, cg0, 0, 0, 0);
            cg1 = __builtin_amdgcn_mfma_f32_16x16x32_bf16(agc, bfr1, cg1, 0, 0, 0);
            c10 = __builtin_amdgcn_mfma_f32_16x16x32_bf16(a1c, bfr0, c10, 0, 0, 0);
            c11 = __builtin_amdgcn_mfma_f32_16x16x32_bf16(a1c, bfr1, c11, 0, 0, 0);
            float4 w2 = *(const float4*)(eg_w2 + t * 16 + kq * 4);
            pd0 += silu_f(cg0[0])*w2.x + silu_f(cg0[1])*w2.y
                 + silu_f(cg0[2])*w2.z + silu_f(cg0[3])*w2.w;
            pd1 += silu_f(cg1[0])*w2.x + silu_f(cg1[1])*w2.y
                 + silu_f(cg1[2])*w2.z + silu_f(cg1[3])*w2.w;
            *(uint2*)(buf + er * 136 + t * 16 + kq * 4) =
                make_uint2(pk2(silu_f(c10[0]), silu_f(c10[1])),
                           pk2(silu_f(c10[2]), silu_f(c10[3])));
            *(uint2*)(buf + (16 + er) * 136 + t * 16 + kq * 4) =
                make_uint2(pk2(silu_f(c11[0]), silu_f(c11[1])),
                           pk2(silu_f(c11[2]), silu_f(c11[3])));
            agc = agn; a1c = a1n;
        }
    }
    pd0 += __shfl_xor(pd0, 16); pd0 += __shfl_xor(pd0, 32);
    pd1 += __shfl_xor(pd1, 16); pd1 += __shfl_xor(pd1, 32);
    const float eb2 = eg_b2[0];
    const float ew0 = cut0 * sigmoid_f(pd0 + eb2);
    const float ew1 = cut1 * sigmoid_f(pd1 + eb2);
    if (lane < 16) {
        ew_s[w * 32 + er] = ew0;       dst_s[w * 32 + er] = dst0;
        ew_s[w * 32 + 16 + er] = ew1;  dst_s[w * 32 + 16 + er] = dst1;
    }

    // ---- L2: distance-2 A-frag prefetch, split accumulator chains ----
    bf16x8 h0[4], h1[4];
    #pragma unroll
    for (int s = 0; s < 4; ++s) {
        h0[s] = *(const bf16x8*)(buf + er * 136 + s * 32 + kq * 8);
        h1[s] = *(const bf16x8*)(buf + (16 + er) * 136 + s * 32 + kq * 8);
    }
    {
        bf16x8 af0[4], af1[4];
        #pragma unroll
        for (int s = 0; s < 4; ++s) {
            af0[s] = *(const bf16x8*)(wp_w2 + (((size_t)s * 8 + 0) * 64 + lane) * 8);
            af1[s] = *(const bf16x8*)(wp_w2 + (((size_t)s * 8 + 1) * 64 + lane) * 8);
        }
        #pragma unroll
        for (int t = 0; t < 8; ++t) {
            const int tn = (t + 2) & 7;
            bf16x8 afn[4];
            #pragma unroll
            for (int s = 0; s < 4; ++s)
                afn[s] = *(const bf16x8*)(wp_w2 + (((size_t)s * 8 + tn) * 64 + lane) * 8);
            float4 b2 = *(const float4*)(wm_b2 + t * 16 + kq * 4);
            f32x4 a0 = {b2.x, b2.y, b2.z, b2.w}, b0 = {0.f, 0.f, 0.f, 0.f};
            f32x4 a1 = a0, b1v = {0.f, 0.f, 0.f, 0.f};
            a0 = __builtin_amdgcn_mfma_f32_16x16x32_bf16(af0[0], h0[0], a0, 0, 0, 0);
            b0 = __builtin_amdgcn_mfma_f32_16x16x32_bf16(af0[2], h0[2], b0, 0, 0, 0);
            a1 = __builtin_amdgcn_mfma_f32_16x16x32_bf16(af0[0], h1[0], a1, 0, 0, 0);
            b1v = __builtin_amdgcn_mfma_f32_16x16x32_bf16(af0[2], h1[2], b1v, 0, 0, 0);
            a0 = __builtin_amdgcn_mfma_f32_16x16x32_bf16(af0[1], h0[1], a0, 0, 0, 0);
            b0 = __builtin_amdgcn_mfma_f32_16x16x32_bf16(af0[3], h0[3], b0, 0, 0, 0);
            a1 = __builtin_amdgcn_mfma_f32_16x16x32_bf16(af0[1], h1[1], a1, 0, 0, 0);
            b1v = __builtin_amdgcn_mfma_f32_16x16x32_bf16(af0[3], h1[3], b1v, 0, 0, 0);
            f32x4 c0 = a0 + b0;
            f32x4 c1 = a1 + b1v;
            *(uint2*)(buf + er * 136 + t * 16 + kq * 4) =
                make_uint2(pk2(silu_f(c0[0]), silu_f(c0[1])),
                           pk2(silu_f(c0[2]), silu_f(c0[3])));
            *(uint2*)(buf + (16 + er) * 136 + t * 16 + kq * 4) =
                make_uint2(pk2(silu_f(c1[0]), silu_f(c1[1])),
                           pk2(silu_f(c1[2]), silu_f(c1[3])));
            #pragma unroll
            for (int s = 0; s < 4; ++s) { af0[s] = af1[s]; af1[s] = afn[s]; }
        }
    }

    // ---- L3 + gather: distance-2 A-frags, distance-1 xv pipeline ----
    #pragma unroll
    for (int s = 0; s < 4; ++s) {
        h0[s] = *(const bf16x8*)(buf + er * 136 + s * 32 + kq * 8);
        h1[s] = *(const bf16x8*)(buf + (16 + er) * 136 + s * 32 + kq * 8);
    }
    const float* xr0 = xn + (size_t)src0 * DD;
    const float* xr1 = xn + (size_t)src1 * DD;
    {
        bf16x8 af0[4], af1[4];
        #pragma unroll
        for (int s = 0; s < 4; ++s) {
            af0[s] = *(const bf16x8*)(wp_w3 + (((size_t)s * 8 + 0) * 64 + lane) * 8);
            af1[s] = *(const bf16x8*)(wp_w3 + (((size_t)s * 8 + 1) * 64 + lane) * 8);
        }
        float4 xv0c = *(const float4*)(xr0 + kq * 4);
        float4 xv1c = *(const float4*)(xr1 + kq * 4);
        #pragma unroll
        for (int t = 0; t < 8; ++t) {
            const int tn = (t + 2) & 7;
            const int tx = (t + 1) & 7;
            bf16x8 afn[4];
            #pragma unroll
            for (int s = 0; s < 4; ++s)
                afn[s] = *(const bf16x8*)(wp_w3 + (((size_t)s * 8 + tn) * 64 + lane) * 8);
            float4 xv0n = *(const float4*)(xr0 + tx * 16 + kq * 4);
            float4 xv1n = *(const float4*)(xr1 + tx * 16 + kq * 4);
            float4 b3 = *(const float4*)(wm_b3 + t * 16 + kq * 4);
            f32x4 a0 = {b3.x, b3.y, b3.z, b3.w}, b0 = {0.f, 0.f, 0.f, 0.f};
            f32x4 a1 = a0, b1v = {0.f, 0.f, 0.f, 0.f};
            a0 = __builtin_amdgcn_mfma_f32_16x16x32_bf16(af0[0], h0[0], a0, 0, 0, 0);
            b0 = __builtin_amdgcn_mfma_f32_16x16x32_bf16(af0[2], h0[2], b0, 0, 0, 0);
            a1 = __builtin_amdgcn_mfma_f32_16x16x32_bf16(af0[0], h1[0], a1, 0, 0, 0);
            b1v = __builtin_amdgcn_mfma_f32_16x16x32_bf16(af0[2], h1[2], b1v, 0, 0, 0);
            a0 = __builtin_amdgcn_mfma_f32_16x16x32_bf16(af0[1], h0[1], a0, 0, 0, 0);
            b0 = __builtin_amdgcn_mfma_f32_16x16x32_bf16(af0[3], h0[3], b0, 0, 0, 0);
            a1 = __builtin_amdgcn_mfma_f32_16x16x32_bf16(af0[1], h1[1], a1, 0, 0, 0);
            b1v = __builtin_amdgcn_mfma_f32_16x16x32_bf16(af0[3], h1[3], b1v, 0, 0, 0);
            f32x4 c0 = a0 + b0;
            f32x4 c1 = a1 + b1v;
            *(uint2*)(buf + er * 136 + t * 16 + kq * 4) =
                make_uint2(pk2(c0[0]*xv0c.x*ew0, c0[1]*xv0c.y*ew0),
                           pk2(c0[2]*xv0c.z*ew0, c0[3]*xv0c.w*ew0));
            *(uint2*)(buf + (16 + er) * 136 + t * 16 + kq * 4) =
                make_uint2(pk2(c1[0]*xv1c.x*ew1, c1[1]*xv1c.y*ew1),
                           pk2(c1[2]*xv1c.z*ew1, c1[3]*xv1c.w*ew1));
            #pragma unroll
            for (int s = 0; s < 4; ++s) { af0[s] = af1[s]; af1[s] = afn[s]; }
            xv0c = xv0n; xv1c = xv1n;
        }
    }

    // ---- per-wave segmented reduce over this wave's 32 dst-sorted rows ----
    {
        const int rb = w * 32;
        float run0 = 0.0f, run1 = 0.0f, ewrun = 0.0f;
        int cur = dst_s[rb];
        #pragma unroll 8
        for (int i = 0; i < 32; ++i) {
            const int d = dst_s[rb + i];
            if (d != cur) {
                atomicAdd(&agg[(size_t)cur * DD + 2 * lane], run0);
                atomicAdd(&agg[(size_t)cur * DD + 2 * lane + 1], run1);
                if (lane == 0) atomicAdd(&nrm[cur], ewrun);
                run0 = 0.0f; run1 = 0.0f; ewrun = 0.0f; cur = d;
            }
            unsigned pv = *(const unsigned*)(buf + i * 136 + 2 * lane);
            run0 += __uint_as_float(pv << 16);
            run1 += __uint_as_float(pv & 0xffff0000u);
            ewrun += ew_s[rb + i];
        }
        atomicAdd(&agg[(size_t)cur * DD + 2 * lane], run0);
        atomicAdd(&agg[(size_t)cur * DD + 2 * lane + 1], run1);
        if (lane == 0) atomicAdd(&nrm[cur], ewrun);
    }
}

// ---------------- Node finalize (MFMA): 64 nodes/block, 16 per wave ---------
__global__ __launch_bounds__(256) void node_kernel(
    const float* __restrict__ x, const float* __restrict__ xn,
    const float* __restrict__ agg, const float* __restrict__ nrm,
    const unsigned short* __restrict__ wp_mm1, const unsigned short* __restrict__ wp_mm2,
    const unsigned short* __restrict__ wp_sl,  const unsigned short* __restrict__ wp_ul,
    const float* __restrict__ mm_b1, const float* __restrict__ mm_b2,
    const float* __restrict__ sl_b, const float* __restrict__ ul_b,
    const float* __restrict__ res_scale, float* __restrict__ out)
{
    __shared__ unsigned short act[4][16 * 136];

    const int tid  = threadIdx.x;
    const int w    = tid >> 6;
    const int lane = tid & 63;
    const int er   = lane & 15;
    const int kq   = lane >> 4;

    const int n0 = blockIdx.x * 64 + w * 16 + er;
    const bool val0 = n0 < N_NODES;
    const int nc0 = val0 ? n0 : N_NODES - 1;

    const float rs0 = __builtin_amdgcn_rcpf(fmaxf(nrm[nc0], 1e-8f));
    const float rscl = res_scale[0];

    bf16x8 ba0[4];
    #pragma unroll
    for (int s = 0; s < 4; ++s) {
        const float4* ap = (const float4*)(agg + (size_t)nc0 * DD + s * 32 + kq * 8);
        float4 a = ap[0], b = ap[1];
        a.x*=rs0; a.y*=rs0; a.z*=rs0; a.w*=rs0; b.x*=rs0; b.y*=rs0; b.z*=rs0; b.w*=rs0;
        ba0[s] = frag8(a, b);
    }

    unsigned short* buf = &act[w][0];

    // mm1 (bias in C-init)
    #pragma unroll
    for (int t = 0; t < 8; ++t) {
        float4 b1 = *(const float4*)(mm_b1 + t * 16 + kq * 4);
        f32x4 c0 = {b1.x, b1.y, b1.z, b1.w};
        #pragma unroll
        for (int s = 0; s < 4; ++s) {
            bf16x8 af = *(const bf16x8*)(wp_mm1 + (((size_t)s * 8 + t) * 64 + lane) * 8);
            c0 = __builtin_amdgcn_mfma_f32_16x16x32_bf16(af, ba0[s], c0, 0, 0, 0);
        }
        *(uint2*)(buf + er * 136 + t * 16 + kq * 4) =
            make_uint2(pk2(silu_f(c0[0]), silu_f(c0[1])),
                       pk2(silu_f(c0[2]), silu_f(c0[3])));
    }

    // mm2 (bias in C-init)
    bf16x8 bh0[4];
    #pragma unroll
    for (int s = 0; s < 4; ++s)
        bh0[s] = *(const bf16x8*)(buf + er * 136 + s * 32 + kq * 8);
    #pragma unroll
    for (int t = 0; t < 8; ++t) {
        float4 b2 = *(const float4*)(mm_b2 + t * 16 + kq * 4);
        f32x4 c0 = {b2.x, b2.y, b2.z, b2.w};
        #pragma unroll
        for (int s = 0; s < 4; ++s) {
            bf16x8 af = *(const bf16x8*)(wp_mm2 + (((size_t)s * 8 + t) * 64 + lane) * 8);
            c0 = __builtin_amdgcn_mfma_f32_16x16x32_bf16(af, bh0[s], c0, 0, 0, 0);
        }
        *(uint2*)(buf + er * 136 + t * 16 + kq * 4) =
            make_uint2(pk2(c0[0], c0[1]), pk2(c0[2], c0[3]));
    }

    bf16x8 bg0[4], bx0[4];
    #pragma unroll
    for (int s = 0; s < 4; ++s) {
        bg0[s] = *(const bf16x8*)(buf + er * 136 + s * 32 + kq * 8);
        const float4* xp = (const float4*)(xn + (size_t)nc0 * DD + s * 32 + kq * 8);
        bx0[s] = frag8(xp[0], xp[1]);
    }

    #pragma unroll
    for (int t = 0; t < 8; ++t) {
        float4 sb = *(const float4*)(sl_b + t * 16 + kq * 4);
        float4 ub = *(const float4*)(ul_b + t * 16 + kq * 4);
        f32x4 c0 = {sb.x + ub.x, sb.y + ub.y, sb.z + ub.z, sb.w + ub.w};
        #pragma unroll
        for (int s = 0; s < 4; ++s) {
            bf16x8 af = *(const bf16x8*)(wp_sl + (((size_t)s * 8 + t) * 64 + lane) * 8);
            c0 = __builtin_amdgcn_mfma_f32_16x16x32_bf16(af, bx0[s], c0, 0, 0, 0);
        }
        #pragma unroll
        for (int s = 0; s < 4; ++s) {
            bf16x8 af = *(const bf16x8*)(wp_ul + (((size_t)s * 8 + t) * 64 + lane) * 8);
            c0 = __builtin_amdgcn_mfma_f32_16x16x32_bf16(af, bg0[s], c0, 0, 0, 0);
        }
        if (val0) {
            float4 xv = *(const float4*)(x + (size_t)n0 * DD + t * 16 + kq * 4);
            float4 o;
            o.x = xv.x + rscl * c0[0];
            o.y = xv.y + rscl * c0[1];
            o.z = xv.z + rscl * c0[2];
            o.w = xv.w + rscl * c0[3];
            *(float4*)(out + (size_t)n0 * DD + t * 16 + kq * 4) = o;
        }
    }
}

extern "C" void kernel_launch(void* const* d_in, const int* in_sizes, int n_in,
                              void* d_out, int out_size, void* d_ws, size_t ws_size,
                              hipStream_t stream) {
    const float* x     = (const float*)d_in[0];
    const int*   esrc  = (const int*)d_in[1];
    const int*   edst  = (const int*)d_in[2];
    // d_in[3] = edge_sh (unused)
    const float* rbf   = (const float*)d_in[4];
    const float* elen  = (const float*)d_in[5];
    const float* ln_g  = (const float*)d_in[6];
    const float* ln_b  = (const float*)d_in[7];
    const float* wm_w1 = (const float*)d_in[8];
    const float* wm_b1 = (const float*)d_in[9];
    const float* wm_w2 = (const float*)d_in[10];
    const float* wm_b2 = (const float*)d_in[11];
    const float* wm_w3 = (const float*)d_in[12];
    const float* wm_b3 = (const float*)d_in[13];
    const float* eg_w1 = (const float*)d_in[14];
    const float* eg_b1 = (const float*)d_in[15];
    const float* eg_w2 = (const float*)d_in[16];
    const float* eg_b2 = (const float*)d_in[17];
    const float* mm_w1 = (const float*)d_in[18];
    const float* mm_b1 = (const float*)d_in[19];
    const float* mm_w2 = (const float*)d_in[20];
    const float* mm_b2 = (const float*)d_in[21];
    const float* sl_w  = (const float*)d_in[22];
    const float* sl_b  = (const float*)d_in[23];
    const float* ul_w  = (const float*)d_in[24];
    const float* ul_b  = (const float*)d_in[25];
    const float* rscl  = (const float*)d_in[26];

    float* xn  = (float*)d_ws;
    float* agg = xn + (size_t)N_NODES * DD;
    float* nrm = agg + (size_t)N_NODES * DD;
    int*   cnt = (int*)(nrm + N_NODES);
    unsigned short* wp = (unsigned short*)(cnt + N_NODES);      // 106496 us
    unsigned short* wp_eg1 = wp;
    unsigned short* wp_w1  = wp + 4096;
    unsigned short* wp_w2  = wp + 8192;
    unsigned short* wp_w3  = wp + 24576;
    unsigned short* wp_mm1 = wp + 40960;
    unsigned short* wp_mm2 = wp + 57344;
    unsigned short* wp_sl  = wp + 73728;
    unsigned short* wp_ul  = wp + 90112;
    int* offs   = (int*)(wp + 106496);
    int* cursor = offs + N_NODES + 1;
    // erec 16B-aligned after cursor
    int4* erec  = (int4*)(((size_t)(cursor + N_NODES) + 15) & ~(size_t)15);

    hipMemsetAsync(agg, 0, (size_t)(N_NODES * DD + 2 * N_NODES) * sizeof(float), stream);
    prep_kernel<<<NPACK + NLN + NHIST, 256, 0, stream>>>(
        eg_w1, wm_w1, wm_w2, wm_w3, mm_w1, mm_w2, sl_w, ul_w, wp,
        x, ln_g, ln_b, xn, edst, elen, cnt);
    scan_kernel<<<1, 1024, 0, stream>>>(cnt, offs, cursor);
    fill_kernel<<<N_EDGES / 256, 256, 0, stream>>>(esrc, edst, elen, cursor, erec);
    edge_seg_kernel<<<N_EDGES / 128, 256, 0, stream>>>(xn, rbf, erec, offs + N_NODES,
        wp_eg1, wp_w1, wp_w2, wp_w3,
        eg_b1, eg_w2, eg_b2, wm_b1, wm_b2, wm_b3, agg, nrm);
    node_kernel<<<(N_NODES + 63) / 64, 256, 0, stream>>>(x, xn, agg, nrm,
        wp_mm1, wp_mm2, wp_sl, wp_ul,
        mm_b1, mm_b2, sl_b, ul_b, rscl, (float*)d_out);
}

// Round 15
// 203.204 us; speedup vs baseline: 1.0127x; 1.0127x over previous
//
#include <hip/hip_runtime.h>
#include <math.h>

#define N_NODES 20000
#define N_EDGES 640000
#define DD 128
#define RR 32
#define HH 128
#define PI_F 3.14159265358979323846f

// prep_kernel block ranges
#define NPACK 416      // 106496 packed weights / 256
#define NLN   5000     // 20000 nodes / 4 rows per block
#define NHIST 2500     // 640000 edges / 256
#define NZERO 2520     // (N_NODES*DD + N_NODES) floats / 4 / 256

typedef short bf16x8 __attribute__((ext_vector_type(8)));
typedef float f32x4 __attribute__((ext_vector_type(4)));
typedef __bf16 bf16x2_t __attribute__((ext_vector_type(2)));

__device__ __forceinline__ float silu_f(float x) {
    return x * __builtin_amdgcn_rcpf(1.0f + __expf(-x));
}
__device__ __forceinline__ float sigmoid_f(float x) {
    return __builtin_amdgcn_rcpf(1.0f + __expf(-x));
}
__device__ __forceinline__ unsigned short f2bf(float x) {
    __bf16 h = (__bf16)x;
    return __builtin_bit_cast(unsigned short, h);
}
__device__ __forceinline__ unsigned pk2(float lo, float hi) {
    bf16x2_t v;
    v[0] = (__bf16)lo; v[1] = (__bf16)hi;
    return __builtin_bit_cast(unsigned, v);
}
__device__ __forceinline__ bf16x8 frag8(float4 a, float4 b) {
    union { unsigned u[4]; bf16x8 v; } r;
    r.u[0] = pk2(a.x, a.y); r.u[1] = pk2(a.z, a.w);
    r.u[2] = pk2(b.x, b.y); r.u[3] = pk2(b.z, b.w);
    return r.v;
}

// pack W[K][F] fp32 -> bf16 MFMA-A-fragment order:
// packed[((s*NT + t)*64 + l)*8 + j] = W[s*32 + (l>>4)*8 + j][t*16 + (l&15)]
__device__ __forceinline__ unsigned short pack_one(const float* __restrict__ src,
                                                   int o, int F) {
    int NT = F >> 4;
    int j = o & 7;
    int l = (o >> 3) & 63;
    int rest = o >> 9;
    int t = rest % NT;
    int s = rest / NT;
    int k = s * 32 + ((l >> 4) << 3) + j;
    int f = t * 16 + (l & 15);
    return f2bf(src[(size_t)k * F + f]);
}

// ---------------- prep: weight packs + LN + histogram + agg zeroing ----------
__global__ __launch_bounds__(256) void prep_kernel(
    const float* __restrict__ eg_w1, const float* __restrict__ wm_w1,
    const float* __restrict__ wm_w2, const float* __restrict__ wm_w3,
    const float* __restrict__ mm_w1, const float* __restrict__ mm_w2,
    const float* __restrict__ sl_w,  const float* __restrict__ ul_w,
    unsigned short* __restrict__ wp,
    const float* __restrict__ x, const float* __restrict__ g,
    const float* __restrict__ b, float* __restrict__ xn,
    const int* __restrict__ edst, const float* __restrict__ elen,
    int* __restrict__ cnt, float4* __restrict__ aggz)
{
    const int blk = blockIdx.x;
    if (blk < NPACK) {
        int o = blk * 256 + threadIdx.x;
        unsigned short v;
        if      (o < 4096)   v = pack_one(eg_w1, o,          HH);
        else if (o < 8192)   v = pack_one(wm_w1, o - 4096,   HH);
        else if (o < 24576)  v = pack_one(wm_w2, o - 8192,   HH);
        else if (o < 40960)  v = pack_one(wm_w3, o - 24576,  DD);
        else if (o < 57344)  v = pack_one(mm_w1, o - 40960,  HH);
        else if (o < 73728)  v = pack_one(mm_w2, o - 57344,  DD);
        else if (o < 90112)  v = pack_one(sl_w,  o - 73728,  DD);
        else                 v = pack_one(ul_w,  o - 90112,  DD);
        wp[o] = v;
    } else if (blk < NPACK + NLN) {
        int wid = ((blk - NPACK) * 256 + threadIdx.x) >> 6;
        int lane = threadIdx.x & 63;
        if (wid >= N_NODES) return;
        const float* row = x + (size_t)wid * DD;
        float v0 = row[lane], v1 = row[lane + 64];
        float s = v0 + v1, sq = v0 * v0 + v1 * v1;
        #pragma unroll
        for (int o = 32; o > 0; o >>= 1) { s += __shfl_xor(s, o); sq += __shfl_xor(sq, o); }
        float mu = s * (1.0f / 128.0f);
        float var = sq * (1.0f / 128.0f) - mu * mu;
        float inv = rsqrtf(var + 1e-5f);
        float* orow = xn + (size_t)wid * DD;
        orow[lane]      = (v0 - mu) * inv * g[lane]      + b[lane];
        orow[lane + 64] = (v1 - mu) * inv * g[lane + 64] + b[lane + 64];
    } else if (blk < NPACK + NLN + NHIST) {
        int e = (blk - NPACK - NLN) * 256 + threadIdx.x;
        if (e < N_EDGES && elen[e] <= 5.0f) atomicAdd(&cnt[edst[e]], 1);
    } else {
        int i = (blk - NPACK - NLN - NHIST) * 256 + threadIdx.x;
        if (i < (N_NODES * DD + N_NODES) / 4)
            aggz[i] = make_float4(0.f, 0.f, 0.f, 0.f);
    }
}

// ---------------- parallel scan over node counts ----------------
__global__ __launch_bounds__(1024) void scan_kernel(const int* __restrict__ cnt,
                                                    int* __restrict__ offs,
                                                    int* __restrict__ cursor) {
    __shared__ int part[1024];
    const int t = threadIdx.x;
    const int per = 20;
    const int base = t * per;
    int s = 0;
    for (int i = 0; i < per; ++i) {
        int idx = base + i;
        if (idx < N_NODES) s += cnt[idx];
    }
    part[t] = s;
    __syncthreads();
    for (int off = 1; off < 1024; off <<= 1) {
        int v = (t >= off) ? part[t - off] : 0;
        __syncthreads();
        part[t] += v;
        __syncthreads();
    }
    int run = part[t] - s;
    for (int i = 0; i < per; ++i) {
        int idx = base + i;
        if (idx < N_NODES) {
            offs[idx] = run;
            cursor[idx] = run;
            run += cnt[idx];
        }
    }
    if (t == 1023) offs[N_NODES] = part[1023];
}

// ---------------- fill: coalesced reads -> 16B edge records at perm pos -----
__global__ __launch_bounds__(256) void fill_kernel(const int* __restrict__ esrc,
                                                   const int* __restrict__ edst,
                                                   const float* __restrict__ elen,
                                                   int* __restrict__ cursor,
                                                   int4* __restrict__ erec) {
    int e = blockIdx.x * 256 + threadIdx.x;
    if (e >= N_EDGES) return;
    float len = elen[e];
    if (len <= 5.0f) {
        int d = edst[e];
        int pos = atomicAdd(&cursor[d], 1);
        float cut = 0.5f * (__cosf(PI_F * len * 0.2f) + 1.0f);
        int4 rec;
        rec.x = e;
        rec.y = esrc[e];
        rec.z = d;
        rec.w = __float_as_int(cut);
        erec[pos] = rec;
    }
}

// ---------------- edge MLP + per-wave segmented scatter (R13 best) ----------
__global__ __launch_bounds__(256, 4) void edge_seg_kernel(
    const float* __restrict__ xn,
    const float* __restrict__ rbf,
    const int4* __restrict__ erec, const int* __restrict__ nlive_p,
    const unsigned short* __restrict__ wp_eg1, const unsigned short* __restrict__ wp_w1,
    const unsigned short* __restrict__ wp_w2,  const unsigned short* __restrict__ wp_w3,
    const float* __restrict__ eg_b1, const float* __restrict__ eg_w2,
    const float* __restrict__ eg_b2,
    const float* __restrict__ wm_b1, const float* __restrict__ wm_b2,
    const float* __restrict__ wm_b3,
    float* __restrict__ agg, float* __restrict__ nrm)
{
    __shared__ unsigned short act[4][32 * 136];
    __shared__ float ew_s[128];
    __shared__ int   dst_s[128];

    const int nlive = nlive_p[0];
    if (blockIdx.x * 128 >= nlive) return;

    const int tid  = threadIdx.x;
    const int w    = tid >> 6;
    const int lane = tid & 63;
    const int er   = lane & 15;
    const int kq   = lane >> 4;

    const int g0 = blockIdx.x * 128 + w * 32 + er;
    const int g1 = g0 + 16;
    const bool v0 = g0 < nlive, v1 = g1 < nlive;
    const int4 r0 = erec[v0 ? g0 : nlive - 1];
    const int4 r1 = erec[v1 ? g1 : nlive - 1];

    const int e0 = r0.x, src0 = r0.y, dst0 = r0.z;
    const int e1 = r1.x, src1 = r1.y, dst1 = r1.z;
    const float cut0 = v0 ? __int_as_float(r0.w) : 0.0f;
    const float cut1 = v1 ? __int_as_float(r1.w) : 0.0f;

    const float4* rp = (const float4*)(rbf + (size_t)e0 * RR + kq * 8);
    bf16x8 bfr0 = frag8(rp[0], rp[1]);
    const float4* rq = (const float4*)(rbf + (size_t)e1 * RR + kq * 8);
    bf16x8 bfr1 = frag8(rq[0], rq[1]);

    unsigned short* buf = &act[w][0];

    // ---- gate + L1 fused, distance-1 A-frag prefetch, bias in C-init ----
    float pd0 = 0.0f, pd1 = 0.0f;
    {
        bf16x8 agc = *(const bf16x8*)(wp_eg1 + (size_t)lane * 8);
        bf16x8 a1c = *(const bf16x8*)(wp_w1  + (size_t)lane * 8);
        #pragma unroll
        for (int t = 0; t < 8; ++t) {
            const int tn = (t + 1) & 7;
            bf16x8 agn = *(const bf16x8*)(wp_eg1 + ((size_t)tn * 64 + lane) * 8);
            bf16x8 a1n = *(const bf16x8*)(wp_w1  + ((size_t)tn * 64 + lane) * 8);
            float4 gb = *(const float4*)(eg_b1 + t * 16 + kq * 4);
            float4 b1 = *(const float4*)(wm_b1 + t * 16 + kq * 4);
            f32x4 cg0 = {gb.x, gb.y, gb.z, gb.w};
            f32x4 cg1 = cg0;
            f32x4 c10 = {b1.x, b1.y, b1.z, b1.w};
            f32x4 c11 = c10;
            cg0 = __builtin_amdgcn_mfma_f32_16x16x32_bf16(agc, bfr0, cg0, 0, 0, 0);
            cg1 = __builtin_amdgcn_mfma_f32_16x16x32_bf16(agc, bfr1, cg1, 0, 0, 0);
            c10 = __builtin_amdgcn_mfma_f32_16x16x32_bf16(a1c, bfr0, c10, 0, 0, 0);
            c11 = __builtin_amdgcn_mfma_f32_16x16x32_bf16(a1c, bfr1, c11, 0, 0, 0);
            float4 w2 = *(const float4*)(eg_w2 + t * 16 + kq * 4);
            pd0 += silu_f(cg0[0])*w2.x + silu_f(cg0[1])*w2.y
                 + silu_f(cg0[2])*w2.z + silu_f(cg0[3])*w2.w;
            pd1 += silu_f(cg1[0])*w2.x + silu_f(cg1[1])*w2.y
                 + silu_f(cg1[2])*w2.z + silu_f(cg1[3])*w2.w;
            *(uint2*)(buf + er * 136 + t * 16 + kq * 4) =
                make_uint2(pk2(silu_f(c10[0]), silu_f(c10[1])),
                           pk2(silu_f(c10[2]), silu_f(c10[3])));
            *(uint2*)(buf + (16 + er) * 136 + t * 16 + kq * 4) =
                make_uint2(pk2(silu_f(c11[0]), silu_f(c11[1])),
                           pk2(silu_f(c11[2]), silu_f(c11[3])));
            agc = agn; a1c = a1n;
        }
    }
    pd0 += __shfl_xor(pd0, 16); pd0 += __shfl_xor(pd0, 32);
    pd1 += __shfl_xor(pd1, 16); pd1 += __shfl_xor(pd1, 32);
    const float eb2 = eg_b2[0];
    const float ew0 = cut0 * sigmoid_f(pd0 + eb2);
    const float ew1 = cut1 * sigmoid_f(pd1 + eb2);
    if (lane < 16) {
        ew_s[w * 32 + er] = ew0;       dst_s[w * 32 + er] = dst0;
        ew_s[w * 32 + 16 + er] = ew1;  dst_s[w * 32 + 16 + er] = dst1;
    }

    // ---- L2: frags to regs, distance-1 prefetch, split accumulator chains ----
    bf16x8 h0[4], h1[4];
    #pragma unroll
    for (int s = 0; s < 4; ++s) {
        h0[s] = *(const bf16x8*)(buf + er * 136 + s * 32 + kq * 8);
        h1[s] = *(const bf16x8*)(buf + (16 + er) * 136 + s * 32 + kq * 8);
    }
    {
        bf16x8 afc[4];
        #pragma unroll
        for (int s = 0; s < 4; ++s)
            afc[s] = *(const bf16x8*)(wp_w2 + ((size_t)(s * 8) * 64 + lane) * 8);
        #pragma unroll
        for (int t = 0; t < 8; ++t) {
            const int tn = (t + 1) & 7;
            bf16x8 afn[4];
            #pragma unroll
            for (int s = 0; s < 4; ++s)
                afn[s] = *(const bf16x8*)(wp_w2 + (((size_t)s * 8 + tn) * 64 + lane) * 8);
            float4 b2 = *(const float4*)(wm_b2 + t * 16 + kq * 4);
            f32x4 a0 = {b2.x, b2.y, b2.z, b2.w}, b0 = {0.f, 0.f, 0.f, 0.f};
            f32x4 a1 = a0, b1v = {0.f, 0.f, 0.f, 0.f};
            a0 = __builtin_amdgcn_mfma_f32_16x16x32_bf16(afc[0], h0[0], a0, 0, 0, 0);
            b0 = __builtin_amdgcn_mfma_f32_16x16x32_bf16(afc[2], h0[2], b0, 0, 0, 0);
            a1 = __builtin_amdgcn_mfma_f32_16x16x32_bf16(afc[0], h1[0], a1, 0, 0, 0);
            b1v = __builtin_amdgcn_mfma_f32_16x16x32_bf16(afc[2], h1[2], b1v, 0, 0, 0);
            a0 = __builtin_amdgcn_mfma_f32_16x16x32_bf16(afc[1], h0[1], a0, 0, 0, 0);
            b0 = __builtin_amdgcn_mfma_f32_16x16x32_bf16(afc[3], h0[3], b0, 0, 0, 0);
            a1 = __builtin_amdgcn_mfma_f32_16x16x32_bf16(afc[1], h1[1], a1, 0, 0, 0);
            b1v = __builtin_amdgcn_mfma_f32_16x16x32_bf16(afc[3], h1[3], b1v, 0, 0, 0);
            f32x4 c0 = a0 + b0;
            f32x4 c1 = a1 + b1v;
            *(uint2*)(buf + er * 136 + t * 16 + kq * 4) =
                make_uint2(pk2(silu_f(c0[0]), silu_f(c0[1])),
                           pk2(silu_f(c0[2]), silu_f(c0[3])));
            *(uint2*)(buf + (16 + er) * 136 + t * 16 + kq * 4) =
                make_uint2(pk2(silu_f(c1[0]), silu_f(c1[1])),
                           pk2(silu_f(c1[2]), silu_f(c1[3])));
            #pragma unroll
            for (int s = 0; s < 4; ++s) afc[s] = afn[s];
        }
    }

    // ---- L3 + gather + bf16 message staging (distance-1, split chains) ----
    #pragma unroll
    for (int s = 0; s < 4; ++s) {
        h0[s] = *(const bf16x8*)(buf + er * 136 + s * 32 + kq * 8);
        h1[s] = *(const bf16x8*)(buf + (16 + er) * 136 + s * 32 + kq * 8);
    }
    const float* xr0 = xn + (size_t)src0 * DD;
    const float* xr1 = xn + (size_t)src1 * DD;
    {
        bf16x8 afc[4];
        #pragma unroll
        for (int s = 0; s < 4; ++s)
            afc[s] = *(const bf16x8*)(wp_w3 + ((size_t)(s * 8) * 64 + lane) * 8);
        #pragma unroll
        for (int t = 0; t < 8; ++t) {
            const int tn = (t + 1) & 7;
            bf16x8 afn[4];
            #pragma unroll
            for (int s = 0; s < 4; ++s)
                afn[s] = *(const bf16x8*)(wp_w3 + (((size_t)s * 8 + tn) * 64 + lane) * 8);
            float4 b3 = *(const float4*)(wm_b3 + t * 16 + kq * 4);
            f32x4 a0 = {b3.x, b3.y, b3.z, b3.w}, b0 = {0.f, 0.f, 0.f, 0.f};
            f32x4 a1 = a0, b1v = {0.f, 0.f, 0.f, 0.f};
            a0 = __builtin_amdgcn_mfma_f32_16x16x32_bf16(afc[0], h0[0], a0, 0, 0, 0);
            b0 = __builtin_amdgcn_mfma_f32_16x16x32_bf16(afc[2], h0[2], b0, 0, 0, 0);
            a1 = __builtin_amdgcn_mfma_f32_16x16x32_bf16(afc[0], h1[0], a1, 0, 0, 0);
            b1v = __builtin_amdgcn_mfma_f32_16x16x32_bf16(afc[2], h1[2], b1v, 0, 0, 0);
            a0 = __builtin_amdgcn_mfma_f32_16x16x32_bf16(afc[1], h0[1], a0, 0, 0, 0);
            b0 = __builtin_amdgcn_mfma_f32_16x16x32_bf16(afc[3], h0[3], b0, 0, 0, 0);
            a1 = __builtin_amdgcn_mfma_f32_16x16x32_bf16(afc[1], h1[1], a1, 0, 0, 0);
            b1v = __builtin_amdgcn_mfma_f32_16x16x32_bf16(afc[3], h1[3], b1v, 0, 0, 0);
            f32x4 c0 = a0 + b0;
            f32x4 c1 = a1 + b1v;
            float4 xv0 = *(const float4*)(xr0 + t * 16 + kq * 4);
            float4 xv1 = *(const float4*)(xr1 + t * 16 + kq * 4);
            *(uint2*)(buf + er * 136 + t * 16 + kq * 4) =
                make_uint2(pk2(c0[0]*xv0.x*ew0, c0[1]*xv0.y*ew0),
                           pk2(c0[2]*xv0.z*ew0, c0[3]*xv0.w*ew0));
            *(uint2*)(buf + (16 + er) * 136 + t * 16 + kq * 4) =
                make_uint2(pk2(c1[0]*xv1.x*ew1, c1[1]*xv1.y*ew1),
                           pk2(c1[2]*xv1.z*ew1, c1[3]*xv1.w*ew1));
            #pragma unroll
            for (int s = 0; s < 4; ++s) afc[s] = afn[s];
        }
    }

    // ---- per-wave segmented reduce over this wave's 32 dst-sorted rows ----
    {
        const int rb = w * 32;
        float run0 = 0.0f, run1 = 0.0f, ewrun = 0.0f;
        int cur = dst_s[rb];
        #pragma unroll 8
        for (int i = 0; i < 32; ++i) {
            const int d = dst_s[rb + i];
            if (d != cur) {
                atomicAdd(&agg[(size_t)cur * DD + 2 * lane], run0);
                atomicAdd(&agg[(size_t)cur * DD + 2 * lane + 1], run1);
                if (lane == 0) atomicAdd(&nrm[cur], ewrun);
                run0 = 0.0f; run1 = 0.0f; ewrun = 0.0f; cur = d;
            }
            unsigned pv = *(const unsigned*)(buf + i * 136 + 2 * lane);
            run0 += __uint_as_float(pv << 16);
            run1 += __uint_as_float(pv & 0xffff0000u);
            ewrun += ew_s[rb + i];
        }
        atomicAdd(&agg[(size_t)cur * DD + 2 * lane], run0);
        atomicAdd(&agg[(size_t)cur * DD + 2 * lane + 1], run1);
        if (lane == 0) atomicAdd(&nrm[cur], ewrun);
    }
}

// ---------------- Node finalize: prefetch + split chains ----------------
__global__ __launch_bounds__(256) void node_kernel(
    const float* __restrict__ x, const float* __restrict__ xn,
    const float* __restrict__ agg, const float* __restrict__ nrm,
    const unsigned short* __restrict__ wp_mm1, const unsigned short* __restrict__ wp_mm2,
    const unsigned short* __restrict__ wp_sl,  const unsigned short* __restrict__ wp_ul,
    const float* __restrict__ mm_b1, const float* __restrict__ mm_b2,
    const float* __restrict__ sl_b, const float* __restrict__ ul_b,
    const float* __restrict__ res_scale, float* __restrict__ out)
{
    __shared__ unsigned short act[4][16 * 136];

    const int tid  = threadIdx.x;
    const int w    = tid >> 6;
    const int lane = tid & 63;
    const int er   = lane & 15;
    const int kq   = lane >> 4;

    const int n0 = blockIdx.x * 64 + w * 16 + er;
    const bool val0 = n0 < N_NODES;
    const int nc0 = val0 ? n0 : N_NODES - 1;

    const float rs0 = __builtin_amdgcn_rcpf(fmaxf(nrm[nc0], 1e-8f));
    const float rscl = res_scale[0];

    bf16x8 ba0[4];
    #pragma unroll
    for (int s = 0; s < 4; ++s) {
        const float4* ap = (const float4*)(agg + (size_t)nc0 * DD + s * 32 + kq * 8);
        float4 a = ap[0], b = ap[1];
        a.x*=rs0; a.y*=rs0; a.z*=rs0; a.w*=rs0; b.x*=rs0; b.y*=rs0; b.z*=rs0; b.w*=rs0;
        ba0[s] = frag8(a, b);
    }

    unsigned short* buf = &act[w][0];

    // mm1 (bias in C-init, distance-1 prefetch, split 2+2 chains)
    {
        bf16x8 afc[4];
        #pragma unroll
        for (int s = 0; s < 4; ++s)
            afc[s] = *(const bf16x8*)(wp_mm1 + ((size_t)(s * 8) * 64 + lane) * 8);
        #pragma unroll
        for (int t = 0; t < 8; ++t) {
            const int tn = (t + 1) & 7;
            bf16x8 afn[4];
            #pragma unroll
            for (int s = 0; s < 4; ++s)
                afn[s] = *(const bf16x8*)(wp_mm1 + (((size_t)s * 8 + tn) * 64 + lane) * 8);
            float4 b1 = *(const float4*)(mm_b1 + t * 16 + kq * 4);
            f32x4 ca = {b1.x, b1.y, b1.z, b1.w}, cb = {0.f, 0.f, 0.f, 0.f};
            ca = __builtin_amdgcn_mfma_f32_16x16x32_bf16(afc[0], ba0[0], ca, 0, 0, 0);
            cb = __builtin_amdgcn_mfma_f32_16x16x32_bf16(afc[2], ba0[2], cb, 0, 0, 0);
            ca = __builtin_amdgcn_mfma_f32_16x16x32_bf16(afc[1], ba0[1], ca, 0, 0, 0);
            cb = __builtin_amdgcn_mfma_f32_16x16x32_bf16(afc[3], ba0[3], cb, 0, 0, 0);
            f32x4 c0 = ca + cb;
            *(uint2*)(buf + er * 136 + t * 16 + kq * 4) =
                make_uint2(pk2(silu_f(c0[0]), silu_f(c0[1])),
                           pk2(silu_f(c0[2]), silu_f(c0[3])));
            #pragma unroll
            for (int s = 0; s < 4; ++s) afc[s] = afn[s];
        }
    }

    // mm2 (bias in C-init, prefetch, split chains)
    bf16x8 bh0[4];
    #pragma unroll
    for (int s = 0; s < 4; ++s)
        bh0[s] = *(const bf16x8*)(buf + er * 136 + s * 32 + kq * 8);
    {
        bf16x8 afc[4];
        #pragma unroll
        for (int s = 0; s < 4; ++s)
            afc[s] = *(const bf16x8*)(wp_mm2 + ((size_t)(s * 8) * 64 + lane) * 8);
        #pragma unroll
        for (int t = 0; t < 8; ++t) {
            const int tn = (t + 1) & 7;
            bf16x8 afn[4];
            #pragma unroll
            for (int s = 0; s < 4; ++s)
                afn[s] = *(const bf16x8*)(wp_mm2 + (((size_t)s * 8 + tn) * 64 + lane) * 8);
            float4 b2 = *(const float4*)(mm_b2 + t * 16 + kq * 4);
            f32x4 ca = {b2.x, b2.y, b2.z, b2.w}, cb = {0.f, 0.f, 0.f, 0.f};
            ca = __builtin_amdgcn_mfma_f32_16x16x32_bf16(afc[0], bh0[0], ca, 0, 0, 0);
            cb = __builtin_amdgcn_mfma_f32_16x16x32_bf16(afc[2], bh0[2], cb, 0, 0, 0);
            ca = __builtin_amdgcn_mfma_f32_16x16x32_bf16(afc[1], bh0[1], ca, 0, 0, 0);
            cb = __builtin_amdgcn_mfma_f32_16x16x32_bf16(afc[3], bh0[3], cb, 0, 0, 0);
            f32x4 c0 = ca + cb;
            *(uint2*)(buf + er * 136 + t * 16 + kq * 4) =
                make_uint2(pk2(c0[0], c0[1]), pk2(c0[2], c0[3]));
            #pragma unroll
            for (int s = 0; s < 4; ++s) afc[s] = afn[s];
        }
    }

    bf16x8 bg0[4], bx0[4];
    #pragma unroll
    for (int s = 0; s < 4; ++s) {
        bg0[s] = *(const bf16x8*)(buf + er * 136 + s * 32 + kq * 8);
        const float4* xp = (const float4*)(xn + (size_t)nc0 * DD + s * 32 + kq * 8);
        bx0[s] = frag8(xp[0], xp[1]);
    }

    // P6: sl ∥ ul independent chains, distance-1 prefetch of both
    {
        bf16x8 slc[4], ulc[4];
        #pragma unroll
        for (int s = 0; s < 4; ++s) {
            slc[s] = *(const bf16x8*)(wp_sl + ((size_t)(s * 8) * 64 + lane) * 8);
            ulc[s] = *(const bf16x8*)(wp_ul + ((size_t)(s * 8) * 64 + lane) * 8);
        }
        #pragma unroll
        for (int t = 0; t < 8; ++t) {
            const int tn = (t + 1) & 7;
            bf16x8 sln[4], uln[4];
            #pragma unroll
            for (int s = 0; s < 4; ++s) {
                sln[s] = *(const bf16x8*)(wp_sl + (((size_t)s * 8 + tn) * 64 + lane) * 8);
                uln[s] = *(const bf16x8*)(wp_ul + (((size_t)s * 8 + tn) * 64 + lane) * 8);
            }
            float4 sb = *(const float4*)(sl_b + t * 16 + kq * 4);
            float4 ub = *(const float4*)(ul_b + t * 16 + kq * 4);
            f32x4 cs = {sb.x + ub.x, sb.y + ub.y, sb.z + ub.z, sb.w + ub.w};
            f32x4 cu = {0.f, 0.f, 0.f, 0.f};
            cs = __builtin_amdgcn_mfma_f32_16x16x32_bf16(slc[0], bx0[0], cs, 0, 0, 0);
            cu = __builtin_amdgcn_mfma_f32_16x16x32_bf16(ulc[0], bg0[0], cu, 0, 0, 0);
            cs = __builtin_amdgcn_mfma_f32_16x16x32_bf16(slc[1], bx0[1], cs, 0, 0, 0);
            cu = __builtin_amdgcn_mfma_f32_16x16x32_bf16(ulc[1], bg0[1], cu, 0, 0, 0);
            cs = __builtin_amdgcn_mfma_f32_16x16x32_bf16(slc[2], bx0[2], cs, 0, 0, 0);
            cu = __builtin_amdgcn_mfma_f32_16x16x32_bf16(ulc[2], bg0[2], cu, 0, 0, 0);
            cs = __builtin_amdgcn_mfma_f32_16x16x32_bf16(slc[3], bx0[3], cs, 0, 0, 0);
            cu = __builtin_amdgcn_mfma_f32_16x16x32_bf16(ulc[3], bg0[3], cu, 0, 0, 0);
            if (val0) {
                float4 xv = *(const float4*)(x + (size_t)n0 * DD + t * 16 + kq * 4);
                float4 o;
                o.x = xv.x + rscl * (cs[0] + cu[0]);
                o.y = xv.y + rscl * (cs[1] + cu[1]);
                o.z = xv.z + rscl * (cs[2] + cu[2]);
                o.w = xv.w + rscl * (cs[3] + cu[3]);
                *(float4*)(out + (size_t)n0 * DD + t * 16 + kq * 4) = o;
            }
            #pragma unroll
            for (int s = 0; s < 4; ++s) { slc[s] = sln[s]; ulc[s] = uln[s]; }
        }
    }
}

extern "C" void kernel_launch(void* const* d_in, const int* in_sizes, int n_in,
                              void* d_out, int out_size, void* d_ws, size_t ws_size,
                              hipStream_t stream) {
    const float* x     = (const float*)d_in[0];
    const int*   esrc  = (const int*)d_in[1];
    const int*   edst  = (const int*)d_in[2];
    // d_in[3] = edge_sh (unused)
    const float* rbf   = (const float*)d_in[4];
    const float* elen  = (const float*)d_in[5];
    const float* ln_g  = (const float*)d_in[6];
    const float* ln_b  = (const float*)d_in[7];
    const float* wm_w1 = (const float*)d_in[8];
    const float* wm_b1 = (const float*)d_in[9];
    const float* wm_w2 = (const float*)d_in[10];
    const float* wm_b2 = (const float*)d_in[11];
    const float* wm_w3 = (const float*)d_in[12];
    const float* wm_b3 = (const float*)d_in[13];
    const float* eg_w1 = (const float*)d_in[14];
    const float* eg_b1 = (const float*)d_in[15];
    const float* eg_w2 = (const float*)d_in[16];
    const float* eg_b2 = (const float*)d_in[17];
    const float* mm_w1 = (const float*)d_in[18];
    const float* mm_b1 = (const float*)d_in[19];
    const float* mm_w2 = (const float*)d_in[20];
    const float* mm_b2 = (const float*)d_in[21];
    const float* sl_w  = (const float*)d_in[22];
    const float* sl_b  = (const float*)d_in[23];
    const float* ul_w  = (const float*)d_in[24];
    const float* ul_b  = (const float*)d_in[25];
    const float* rscl  = (const float*)d_in[26];

    float* xn  = (float*)d_ws;
    float* agg = xn + (size_t)N_NODES * DD;
    float* nrm = agg + (size_t)N_NODES * DD;
    int*   cnt = (int*)(nrm + N_NODES);
    unsigned short* wp = (unsigned short*)(cnt + N_NODES);      // 106496 us
    unsigned short* wp_eg1 = wp;
    unsigned short* wp_w1  = wp + 4096;
    unsigned short* wp_w2  = wp + 8192;
    unsigned short* wp_w3  = wp + 24576;
    unsigned short* wp_mm1 = wp + 40960;
    unsigned short* wp_mm2 = wp + 57344;
    unsigned short* wp_sl  = wp + 73728;
    unsigned short* wp_ul  = wp + 90112;
    int* offs   = (int*)(wp + 106496);
    int* cursor = offs + N_NODES + 1;
    // erec 16B-aligned after cursor
    int4* erec  = (int4*)(((size_t)(cursor + N_NODES) + 15) & ~(size_t)15);

    hipMemsetAsync(cnt, 0, (size_t)N_NODES * sizeof(int), stream);
    prep_kernel<<<NPACK + NLN + NHIST + NZERO, 256, 0, stream>>>(
        eg_w1, wm_w1, wm_w2, wm_w3, mm_w1, mm_w2, sl_w, ul_w, wp,
        x, ln_g, ln_b, xn, edst, elen, cnt, (float4*)agg);
    scan_kernel<<<1, 1024, 0, stream>>>(cnt, offs, cursor);
    fill_kernel<<<N_EDGES / 256, 256, 0, stream>>>(esrc, edst, elen, cursor, erec);
    edge_seg_kernel<<<N_EDGES / 128, 256, 0, stream>>>(xn, rbf, erec, offs + N_NODES,
        wp_eg1, wp_w1, wp_w2, wp_w3,
        eg_b1, eg_w2, eg_b2, wm_b1, wm_b2, wm_b3, agg, nrm);
    node_kernel<<<(N_NODES + 63) / 64, 256, 0, stream>>>(x, xn, agg, nrm,
        wp_mm1, wp_mm2, wp_sl, wp_ul,
        mm_b1, mm_b2, sl_b, ul_b, rscl, (float*)d_out);
}